// Round 10
// baseline (451.101 us; speedup 1.0000x reference)
//
#include <hip/hip_runtime.h>
#include <math.h>

#define Bn 4096
#define Tn 512
#define Vn 57
#define En 20
#define Hn 128
#define On 18
#define ROWS 16          // batch rows per block (= MFMA N)
#define NTHR 512         // 8 waves = 2/SIMD: spreads fixed per-step trans/MFMA work
#define NBLK (Bn / ROWS) // 256 blocks -> 1 per CU (LDS pad keeps it that way)
#define XWSTR 132        // xw table row stride (floats), 16B-aligned rows
#define XBSTR 516        // id byte-row stride: word bank = (n + t/4) % 32, conflict-free
#define HFSTR 132        // final-h fp32 row stride
#define ASCALE 2.8853900817779268f   // 2*log2(e): folds tanh's 2x and log2e mul in
#define TAGM  0x40000000u            // bit30 = bit14 of high fp16 = exp MSB, always 0 for |h|<2

typedef _Float16 half8  __attribute__((ext_vector_type(8)));
typedef __fp16   fp16x2 __attribute__((ext_vector_type(2)));   // cvt_pkrtz native type
typedef float    floatx4 __attribute__((ext_vector_type(4)));

// acc is pre-scaled by 2*log2e: tanh(x) = 1 - 2/(1+2^(2x*log2e))
__device__ __forceinline__ float tanh_scaled(float z) {
    float e = __builtin_amdgcn_exp2f(z);          // v_exp_f32
    float r = __builtin_amdgcn_rcpf(e + 1.0f);    // v_rcp_f32
    return fmaf(-2.0f, r, 1.0f);
}

__device__ __forceinline__ unsigned pk_u32(fp16x2 v) {
    union { fp16x2 h; unsigned u; } c; c.h = v; return c.u;
}

__device__ __forceinline__ half8 as_half8(uint4 v) {
    union { uint4 u; half8 h; } c; c.u = v; return c.h;
}

// (512, 2): 8 waves = 2/EU -> VGPR cap 256; demand ~65 -> no spill.
__launch_bounds__(NTHR, 2)
__global__ void rnn_mfma_kernel(const int* __restrict__ x,
                                const int* __restrict__ xlen,
                                const float* __restrict__ emb,
                                const float* __restrict__ W_ih,
                                const float* __restrict__ W_hh,
                                const float* __restrict__ b_ih,
                                const float* __restrict__ b_hh,
                                const float* __restrict__ W_out,
                                const float* __restrict__ b_out,
                                float* __restrict__ out)
{
    // SELF-VALIDATING state exchange (no barrier, no flags): h-fragment kc for
    // lane l at exB[buf][kc][l] (uint4 = half8, k = 32kc+8q+j, batch col n=l&15).
    // Each wave's 8B uint2 carries a step tag in bit30 of its .y word (= bit14
    // of h3's fp16; always 0 since |h|<=1, so setting it is fully reversible).
    // Readers issue the b128 frag reads UNCONDITIONALLY, validate the 8 tags
    // in-register, clear them, and retry on staleness -- the sync release rides
    // the data read instead of preceding it (R9 lesson: a control-dependent
    // poll read adds its full latency to the chain).
    //   Ring/tag scheme: step t reads S(t) in slot t%2 expecting tag (t>>1)&1,
    //   writes S(t+1) to slot (t+1)%2 with tag ((t+1)>>1)&1. Slot reuse period
    //   2 alternates the tag, so stale always differs. Prefill: slot0 = S(0)=0
    //   (tag 0 valid), slot1 tag-poisoned (bit30 set).
    //   Lead bound / WAR: wave writes S(t+2) only after validating ALL waves'
    //   S(t+1), which each published only after reading S(t) -> overwriting
    //   S(t)'s slot is safe; max inter-wave lead = 1 < ring depth 2. Deadlock-
    //   free: the minimum-progress wave's needed tags are always published.
    //   RAW per wave: own write precedes own next-step reads in the in-order
    //   DS stream; cross-wave freshness is exactly what tags certify.
    __shared__ __align__(16) uint4 exB[2][4][64];
    __shared__ __align__(16) float sXW[Vn * XWSTR];   // xw[id][f] = (W_ih.emb[id]+b)*ASCALE
    __shared__ __align__(16) float sHf[ROWS * HFSTR];
    __shared__ __align__(16) unsigned char sXb[ROWS * XBSTR];  // token ids as bytes
    __shared__ float sLogit[ROWS][On];
    __shared__ float sMLS[ROWS];
    __shared__ float sPad[6200];   // 24.8KB pad: total ~81KB -> exactly 1 block/CU

    const int tid  = threadIdx.x;
    const int blk  = blockIdx.x;
    const int row0 = blk * ROWS;

    // volatile touch keeps sPad (and the 1-block/CU LDS footprint) alive
    ((volatile float*)sPad)[tid % 6200] = 0.0f;

    const int w    = tid >> 6;       // wave 0..7 -> owns 16 h features
    const int lane = tid & 63;
    const int n    = lane & 15;      // batch col (B/C) AND A fragment row m
    const int q    = lane >> 4;      // quad
    const int kcW  = w >> 1;         // which 32-k fragment this wave's output feeds
    const int bsel = w & 1;          // which uint2 half of the 16B frag slot

    // ---- A operand (static, 16 VGPRs): PERMUTED row map so C output reg i of
    // lane (q,n) == h feature F = 32*kcW + 8q + 4*bsel + i; the packed tanh
    // output (uint2) is EXACTLY the right 8B of B-fragment kcW -- no cross-lane
    // movement, one ds_write_b64 per lane per step.
    //   A row m = lane&15 loads weight row F(m) = 32*kcW + 8*(m>>2) + 4*bsel + (m&3).
    // Input projection comes from the f32 XW table as accumulator init.
    // Pre-scaled by 2*log2e (tanh input fusion).
    half8 Ah[4];
    const int f = 32 * kcW + 8 * (n >> 2) + 4 * bsel + (n & 3);
    #pragma unroll
    for (int kc = 0; kc < 4; ++kc) {
        const float* p = &W_hh[f * Hn + kc * 32 + q * 8];
        #pragma unroll
        for (int i = 0; i < 8; ++i)
            Ah[kc][i] = (_Float16)(p[i] * ASCALE);
    }

    // ---- xw lookup table (f32, exact): input projection folded to a 57-entry LUT
    for (int idx = tid; idx < Vn * Hn; idx += NTHR) {
        int vo = idx >> 7, ff = idx & 127;
        float acc = b_ih[ff] + b_hh[ff];
        #pragma unroll
        for (int e = 0; e < En; ++e)
            acc = fmaf(emb[vo * En + e], W_ih[ff * En + e], acc);
        sXW[vo * XWSTR + ff] = acc * ASCALE;
    }
    // ---- stage vocab ids as bytes (vocab=57 < 256); int4 load, uchar4 store
    for (int idx = tid * 4; idx < ROWS * Tn; idx += NTHR * 4) {
        int4 v = *(const int4*)&x[row0 * Tn + idx];
        int r = idx >> 9, t = idx & 511;
        uchar4 bb;
        bb.x = (unsigned char)v.x; bb.y = (unsigned char)v.y;
        bb.z = (unsigned char)v.z; bb.w = (unsigned char)v.w;
        *(uchar4*)&sXb[r * XBSTR + t] = bb;
    }
    // ---- prefill: buf0 = S(0) = zeros (tag 0 = valid); buf1 tag-poisoned
    for (int idx = tid; idx < 2 * 4 * 64; idx += NTHR) {
        uint4 z = make_uint4(0u, 0u, 0u, 0u);
        if (idx >= 4 * 64) { z.y = TAGM; z.w = TAGM; }
        ((uint4*)exB)[idx] = z;
    }
    __syncthreads();   // prologue barrier: everything above visible to all waves

    const int Lmax  = xlen[row0];        // sorted descending -> block trip count
    const int len_n = xlen[row0 + n];    // per batch-col freeze point
    const int wOffH = 32 * kcW + 8 * q + 4 * bsel;   // this lane's feature base

    // ---- xw pipeline: prefetched one step ahead (off the critical chain)
    int    idN;
    float4 XWc;
    {
        int id0 = sXb[n * XBSTR];
        XWc = *(const float4*)&sXW[id0 * XWSTR + wOffH];
        idN = sXb[n * XBSTR + (Lmax > 1 ? 1 : 0)];
    }
    float hreg[4] = {0.f, 0.f, 0.f, 0.f};

    // one step, barrier-free: prefetch xw/id for t+1; read 4 b128 frags and
    // validate embedded tags (retry if any writer hasn't landed); clear tags;
    // 4 MFMA depth-2 E/O (aE init = f32 xw); tanh+freeze+pack; tag own .y;
    // single ds_write_b64 publish. RT/WT = read/write tag bits (wave-uniform).
    #define RNN_STEP(BR, BW, t, RT, WT)                                           \
    {                                                                             \
        float4 XWn = *(const float4*)&sXW[idN * XWSTR + wOffH];                   \
        int tn = (t) + 2;                                                         \
        int idN2 = sXb[n * XBSTR + (tn < Lmax ? tn : Lmax - 1)];                  \
        const unsigned et = (RT) << 30;                                           \
        uint4 u0, u1, u2, u3;                                                     \
        for (;;) {                                                                \
            __asm__ __volatile__("" ::: "memory");                                \
            u0 = exB[BR][0][lane];                                                \
            u1 = exB[BR][1][lane];                                                \
            u2 = exB[BR][2][lane];                                                \
            u3 = exB[BR][3][lane];                                                \
            unsigned stale = ((u0.y ^ et) | (u0.w ^ et) | (u1.y ^ et) |           \
                              (u1.w ^ et) | (u2.y ^ et) | (u2.w ^ et) |           \
                              (u3.y ^ et) | (u3.w ^ et)) & TAGM;                  \
            if (!__any((int)stale)) break;                                        \
        }                                                                         \
        u0.y &= ~TAGM; u0.w &= ~TAGM; u1.y &= ~TAGM; u1.w &= ~TAGM;               \
        u2.y &= ~TAGM; u2.w &= ~TAGM; u3.y &= ~TAGM; u3.w &= ~TAGM;               \
        half8 bf0 = as_half8(u0), bf1 = as_half8(u1);                             \
        half8 bf2 = as_half8(u2), bf3 = as_half8(u3);                             \
        floatx4 aE = {XWc.x, XWc.y, XWc.z, XWc.w};                                \
        floatx4 aO = {0.f, 0.f, 0.f, 0.f};                                        \
        aE = __builtin_amdgcn_mfma_f32_16x16x32_f16(Ah[0], bf0, aE, 0, 0, 0);     \
        aO = __builtin_amdgcn_mfma_f32_16x16x32_f16(Ah[1], bf1, aO, 0, 0, 0);     \
        aE = __builtin_amdgcn_mfma_f32_16x16x32_f16(Ah[2], bf2, aE, 0, 0, 0);     \
        aO = __builtin_amdgcn_mfma_f32_16x16x32_f16(Ah[3], bf3, aO, 0, 0, 0);     \
        const bool upd = ((t) < len_n);                                           \
        _Pragma("unroll")                                                         \
        for (int i = 0; i < 4; ++i) {                                             \
            float v = tanh_scaled(aE[i] + aO[i]);                                 \
            hreg[i] = upd ? v : hreg[i];                                          \
        }                                                                         \
        uint2 pk;                                                                 \
        pk.x = pk_u32(__builtin_amdgcn_cvt_pkrtz(hreg[0], hreg[1]));              \
        pk.y = pk_u32(__builtin_amdgcn_cvt_pkrtz(hreg[2], hreg[3]))               \
               | ((WT) << 30);                                                    \
        *(uint2*)((_Float16*)&exB[BW][kcW][0] + lane * 8 + 4 * bsel) = pk;        \
        XWc = XWn; idN = idN2;                                                    \
    }

    unsigned e = 0u;
    int t = 0;
    for (; t + 2 <= Lmax; t += 2) {
        RNN_STEP(0, 1, t,     e, e);        // even step: writes S(t+1), tag e
        RNN_STEP(1, 0, t + 1, e, e ^ 1u);   // odd step: writes S(t+2), tag e^1
        e ^= 1u;
    }
    if (t < Lmax) {
        RNN_STEP(0, 1, t, e, e);
    }
    #undef RNN_STEP

    // ---- publish final fp32 h: lane (q,n) of wave w holds features wOffH+0..3
    {
        float4 f0;
        f0.x = hreg[0]; f0.y = hreg[1]; f0.z = hreg[2]; f0.w = hreg[3];
        *(float4*)&sHf[n * HFSTR + wOffH] = f0;
    }
    __syncthreads();

    // ---- epilogue: logits = relu(h) @ W_out^T + b_out, then log_softmax
    for (int it = tid; it < ROWS * On; it += NTHR) {
        int r = it / On, c = it % On;
        float acc = b_out[c];
        for (int k = 0; k < Hn; ++k) {
            float hv = sHf[r * HFSTR + k];
            hv = hv > 0.0f ? hv : 0.0f;
            acc = fmaf(hv, W_out[c * Hn + k], acc);
        }
        sLogit[r][c] = acc;
    }
    __syncthreads();

    if (tid < ROWS) {
        float m = -INFINITY;
        #pragma unroll
        for (int c = 0; c < On; ++c) m = fmaxf(m, sLogit[tid][c]);
        float s = 0.0f;
        #pragma unroll
        for (int c = 0; c < On; ++c) s += __expf(sLogit[tid][c] - m);
        sMLS[tid] = m + __logf(s);
    }
    __syncthreads();

    for (int it = tid; it < ROWS * On; it += NTHR) {
        int r = it / On, c = it % On;
        out[(row0 + r) * On + c] = sLogit[r][c] - sMLS[r];
    }
}

extern "C" void kernel_launch(void* const* d_in, const int* in_sizes, int n_in,
                              void* d_out, int out_size, void* d_ws, size_t ws_size,
                              hipStream_t stream) {
    const int*   x     = (const int*)d_in[0];
    const int*   xlen  = (const int*)d_in[1];
    const float* emb   = (const float*)d_in[2];
    const float* W_ih  = (const float*)d_in[3];
    const float* W_hh  = (const float*)d_in[4];
    const float* b_ih  = (const float*)d_in[5];
    const float* b_hh  = (const float*)d_in[6];
    const float* W_out = (const float*)d_in[7];
    const float* b_out = (const float*)d_in[8];
    float*       out   = (float*)d_out;

    rnn_mfma_kernel<<<NBLK, NTHR, 0, stream>>>(x, xlen, emb, W_ih, W_hh,
                                               b_ih, b_hh, W_out, b_out, out);
}

// Round 11
// 315.194 us; speedup vs baseline: 1.4312x; 1.4312x over previous
//
#include <hip/hip_runtime.h>
#include <math.h>

#define Bn 4096
#define Tn 512
#define Vn 57
#define En 20
#define Hn 128
#define On 18
#define ROWS 32          // batch rows per block = 2 independent groups of 16
#define NTHR 512         // 8 waves: waves 0-3 -> group A, 4-7 -> group B (1 A + 1 B per SIMD)
#define NBLK (Bn / ROWS) // 128 blocks, 1 per CU (LDS pad enforces exclusivity)
#define KC 5             // A K-chunks: 4x32 (W_hh) + 1x32 (W_ih 20 + bias 1 + 11 pad)
#define ESTR 40          // embT row stride (halfs) -- champion value
#define XBSTR 516        // id byte-row stride: word bank = (row + t/4) % 32, conflict-free
#define HFSTR 132        // final-h fp32 row stride
#define ASCALE 2.8853900817779268f   // 2*log2(e): folds tanh's 2x and log2e mul into A

typedef _Float16 half8  __attribute__((ext_vector_type(8)));
typedef __fp16   fp16x2 __attribute__((ext_vector_type(2)));   // cvt_pkrtz native type
typedef float    floatx4 __attribute__((ext_vector_type(4)));

// acc is pre-scaled by 2*log2e: tanh(x) = 1 - 2/(1+2^(2x*log2e))
__device__ __forceinline__ float tanh_scaled(float z) {
    float e = __builtin_amdgcn_exp2f(z);          // v_exp_f32
    float r = __builtin_amdgcn_rcpf(e + 1.0f);    // v_rcp_f32
    return fmaf(-2.0f, r, 1.0f);
}

__device__ __forceinline__ unsigned pk_u32(fp16x2 v) {
    union { fp16x2 h; unsigned u; } c; c.h = v; return c.u;
}

__device__ __forceinline__ half8 as_half8(uint4 v) {
    union { uint4 u; half8 h; } c; c.u = v; return c.h;
}

// (512, 2): 8 waves = 2/EU -> VGPR cap 256; demand ~100 (A 40 + P 8 + hreg 8 +
// own 4 + accs 16 + misc), all statically indexed -> no spill (R4 lesson).
__launch_bounds__(NTHR, 2)
__global__ void rnn_mfma_kernel(const int* __restrict__ x,
                                const int* __restrict__ xlen,
                                const float* __restrict__ emb,
                                const float* __restrict__ W_ih,
                                const float* __restrict__ W_hh,
                                const float* __restrict__ b_ih,
                                const float* __restrict__ b_hh,
                                const float* __restrict__ W_out,
                                const float* __restrict__ b_out,
                                float* __restrict__ out)
{
    // Per-group exchange: frag j for lane l at exB[G][buf][j][l] (uint4=half8,
    // k = 32j+8q+jj, batch col n=l&15 of group G). Each wave OWNS one full frag
    // (feeds its MFMA from registers, zero-wait at barrier release) and reads
    // only the 3 foreign frags (48B/lane; CU burst 24KB for TWO chain-steps vs
    // champion's 32KB for one). One shared barrier retires one step of BOTH
    // independent chains; A/B waves on each SIMD fill each other's stalls.
    __shared__ __align__(16) uint4 exB[2][2][4][64];
    __shared__ __align__(16) _Float16 sEmb[Vn * ESTR];  // cols 0..19 emb, 20 = 1.0, rest 0
    __shared__ __align__(16) float sHf[ROWS * HFSTR];
    __shared__ __align__(16) unsigned char sXb[ROWS * XBSTR];  // token ids as bytes
    __shared__ float sLogit[ROWS][On];
    __shared__ float sMLS[ROWS];
    __shared__ float sPad[6200];   // 24.8KB pad: total ~81.6KB -> exactly 1 block/CU

    const int tid  = threadIdx.x;
    const int blk  = blockIdx.x;
    const int row0 = blk * ROWS;

    // volatile touch keeps sPad (and the 1-block/CU LDS footprint) alive
    ((volatile float*)sPad)[tid % 6200] = 0.0f;

    const int w    = tid >> 6;       // wave 0..7
    const int lane = tid & 63;
    const int G    = w >> 2;         // group 0 (rows +0..15) / 1 (rows +16..31)
    const int g    = w & 3;          // owned fragment index (features 32g..32g+31)
    const int n    = lane & 15;      // batch col within group AND A fragment row m
    const int q    = lane >> 4;      // quad
    const int rloc = G * 16 + n;     // block-local batch row

    // ---- A operand (static, 40 VGPRs): 2 tiles x 5 chunks, PERMUTED row map
    //   F(tau, m) = 32g + 8*(m>>2) + 4*tau + (m&3)
    // so C reg i of tile tau at lane (q,n) == h feature 32g + 8q + 4tau + i;
    // the packed tanh output (uint4) is EXACTLY B-fragment g. Local chunk c
    // pairs with global k-chunk (g+c)&3 (c=0 -> own fragment, register-fed);
    // c=4 is the W_ih/bias chunk (constant-1 xe col 20). Pre-scaled by 2*log2e.
    half8 Ah[2][KC];
    #pragma unroll
    for (int tau = 0; tau < 2; ++tau) {
        const int f = 32 * g + 8 * (n >> 2) + 4 * tau + (n & 3);
        #pragma unroll
        for (int c = 0; c < 4; ++c) {
            const int kc = (g + c) & 3;
            const float* p = &W_hh[f * Hn + kc * 32 + q * 8];
            #pragma unroll
            for (int i = 0; i < 8; ++i)
                Ah[tau][c][i] = (_Float16)(p[i] * ASCALE);
        }
        #pragma unroll
        for (int i = 0; i < 8; ++i) {
            int e = q * 8 + i;
            float v = 0.0f;
            if (e < En)       v = W_ih[f * En + e];
            else if (e == 20) v = b_ih[f] + b_hh[f];
            Ah[tau][4][i] = (_Float16)(v * ASCALE);
        }
    }

    // ---- build embT (fp16) with constant-1 bias column
    for (int idx = tid; idx < Vn * 32; idx += NTHR) {
        int c = idx >> 5, j = idx & 31;
        float v = (j < En) ? emb[c * En + j] : (j == 20 ? 1.0f : 0.0f);
        sEmb[c * ESTR + j] = (_Float16)v;
    }
    // ---- stage vocab ids as bytes (vocab=57 < 256); int4 load, uchar4 store
    for (int idx = tid * 4; idx < ROWS * Tn; idx += NTHR * 4) {
        int4 v = *(const int4*)&x[row0 * Tn + idx];
        int r = idx >> 9, t = idx & 511;
        uchar4 bb;
        bb.x = (unsigned char)v.x; bb.y = (unsigned char)v.y;
        bb.z = (unsigned char)v.z; bb.w = (unsigned char)v.w;
        *(uchar4*)&sXb[r * XBSTR + t] = bb;
    }
    // ---- zero all exchange buffers (h0 = 0)
    for (int idx = tid; idx < 2 * 2 * 4 * 64; idx += NTHR)
        ((uint4*)exB)[idx] = make_uint4(0u, 0u, 0u, 0u);
    __syncthreads();

    const int Lmax  = xlen[row0];          // block trip count (sorted desc)
    const int len_n = xlen[row0 + rloc];   // per batch-col freeze point

    // ---- xe pipeline (champion structure): the xe MFMA partials P0/P1 for the
    // next step are pre-accumulated BEFORE the barrier; the write-drain hides
    // under the xe gather (in-order per-wave DS returns).
    int     idN;
    floatx4 P0 = {0.f, 0.f, 0.f, 0.f}, P1 = {0.f, 0.f, 0.f, 0.f};
    {
        int id0 = sXb[rloc * XBSTR];
        half8 xe0 = *(const half8*)&sEmb[id0 * ESTR + 8 * q];
        P0 = __builtin_amdgcn_mfma_f32_16x16x32_f16(Ah[0][4], xe0, P0, 0, 0, 0);
        P1 = __builtin_amdgcn_mfma_f32_16x16x32_f16(Ah[1][4], xe0, P1, 0, 0, 0);
        idN = sXb[rloc * XBSTR + (Lmax > 1 ? 1 : 0)];
    }

    uint4 own = make_uint4(0u, 0u, 0u, 0u);  // own fragment g (h0 = 0)
    float hreg[8] = {0.f, 0.f, 0.f, 0.f, 0.f, 0.f, 0.f, 0.f};

    const int j1 = (g + 1) & 3, j2 = (g + 2) & 3, j3 = (g + 3) & 3;

    // one step: issue 3 foreign b128 reads; own-frag MFMAs fire at zero wait
    // (register operand) and fill the read latency; 6 more MFMAs staged on the
    // returning frags (aE: P+own+c2, aO: c1+c3 per tile); tanh+freeze; pack one
    // uint4 (== frag g) -> single b128 publish + keep in regs; xe gather covers
    // the write drain; P-MFMAs for t+1; ONE barrier for both groups.
    #define RNN_STEP(BR, BW, t)                                                     \
    {                                                                               \
        half8 bf1 = *(const half8*)&exB[G][BR][j1][lane];                           \
        half8 bf2 = *(const half8*)&exB[G][BR][j2][lane];                           \
        half8 bf3 = *(const half8*)&exB[G][BR][j3][lane];                           \
        half8 bo  = as_half8(own);                                                  \
        floatx4 aE0 = __builtin_amdgcn_mfma_f32_16x16x32_f16(Ah[0][0], bo, P0, 0,0,0); \
        floatx4 aE1 = __builtin_amdgcn_mfma_f32_16x16x32_f16(Ah[1][0], bo, P1, 0,0,0); \
        floatx4 z0 = {0.f, 0.f, 0.f, 0.f};                                          \
        floatx4 aO0 = __builtin_amdgcn_mfma_f32_16x16x32_f16(Ah[0][1], bf1, z0, 0,0,0); \
        floatx4 aO1 = __builtin_amdgcn_mfma_f32_16x16x32_f16(Ah[1][1], bf1, z0, 0,0,0); \
        aE0 = __builtin_amdgcn_mfma_f32_16x16x32_f16(Ah[0][2], bf2, aE0, 0, 0, 0);  \
        aE1 = __builtin_amdgcn_mfma_f32_16x16x32_f16(Ah[1][2], bf2, aE1, 0, 0, 0);  \
        aO0 = __builtin_amdgcn_mfma_f32_16x16x32_f16(Ah[0][3], bf3, aO0, 0, 0, 0);  \
        aO1 = __builtin_amdgcn_mfma_f32_16x16x32_f16(Ah[1][3], bf3, aO1, 0, 0, 0);  \
        const bool upd = ((t) < len_n);                                             \
        _Pragma("unroll")                                                           \
        for (int i = 0; i < 4; ++i) {                                               \
            float v0 = tanh_scaled(aE0[i] + aO0[i]);                                \
            float v1 = tanh_scaled(aE1[i] + aO1[i]);                                \
            hreg[i]     = upd ? v0 : hreg[i];                                       \
            hreg[4 + i] = upd ? v1 : hreg[4 + i];                                   \
        }                                                                           \
        uint4 pk;                                                                   \
        pk.x = pk_u32(__builtin_amdgcn_cvt_pkrtz(hreg[0], hreg[1]));                \
        pk.y = pk_u32(__builtin_amdgcn_cvt_pkrtz(hreg[2], hreg[3]));                \
        pk.z = pk_u32(__builtin_amdgcn_cvt_pkrtz(hreg[4], hreg[5]));                \
        pk.w = pk_u32(__builtin_amdgcn_cvt_pkrtz(hreg[6], hreg[7]));                \
        exB[G][BW][g][lane] = pk;                                                   \
        own = pk;                                                                   \
        half8 xeN = *(const half8*)&sEmb[idN * ESTR + 8 * q];                       \
        int tn = (t) + 2;                                                           \
        int idN2 = sXb[rloc * XBSTR + (tn < Lmax ? tn : Lmax - 1)];                 \
        P0 = __builtin_amdgcn_mfma_f32_16x16x32_f16(Ah[0][4], xeN, z0, 0, 0, 0);    \
        P1 = __builtin_amdgcn_mfma_f32_16x16x32_f16(Ah[1][4], xeN, z0, 0, 0, 0);    \
        idN = idN2;                                                                 \
        __syncthreads();                                                            \
    }

    int t = 0;
    for (; t + 2 <= Lmax; t += 2) {
        RNN_STEP(0, 1, t);
        RNN_STEP(1, 0, t + 1);
    }
    if (t < Lmax) {
        RNN_STEP(0, 1, t);
    }
    #undef RNN_STEP

    // ---- publish final fp32 h: lane (q,n) of wave (G,g) holds features
    // 32g + 8q + 4*tau + i (tau=0 -> hreg[0..3], tau=1 -> hreg[4..7]).
    {
        float4 f0;
        f0.x = hreg[0]; f0.y = hreg[1]; f0.z = hreg[2]; f0.w = hreg[3];
        *(float4*)&sHf[rloc * HFSTR + 32 * g + 8 * q] = f0;
        f0.x = hreg[4]; f0.y = hreg[5]; f0.z = hreg[6]; f0.w = hreg[7];
        *(float4*)&sHf[rloc * HFSTR + 32 * g + 8 * q + 4] = f0;
    }
    __syncthreads();

    // ---- epilogue: logits = relu(h) @ W_out^T + b_out, then log_softmax
    for (int it = tid; it < ROWS * On; it += NTHR) {
        int r = it / On, c = it % On;
        float acc = b_out[c];
        for (int k = 0; k < Hn; ++k) {
            float hv = sHf[r * HFSTR + k];
            hv = hv > 0.0f ? hv : 0.0f;
            acc = fmaf(hv, W_out[c * Hn + k], acc);
        }
        sLogit[r][c] = acc;
    }
    __syncthreads();

    if (tid < ROWS) {
        float m = -INFINITY;
        #pragma unroll
        for (int c = 0; c < On; ++c) m = fmaxf(m, sLogit[tid][c]);
        float s = 0.0f;
        #pragma unroll
        for (int c = 0; c < On; ++c) s += __expf(sLogit[tid][c] - m);
        sMLS[tid] = m + __logf(s);
    }
    __syncthreads();

    for (int it = tid; it < ROWS * On; it += NTHR) {
        int r = it / On, c = it % On;
        out[(row0 + r) * On + c] = sLogit[r][c] - sMLS[r];
    }
}

extern "C" void kernel_launch(void* const* d_in, const int* in_sizes, int n_in,
                              void* d_out, int out_size, void* d_ws, size_t ws_size,
                              hipStream_t stream) {
    const int*   x     = (const int*)d_in[0];
    const int*   xlen  = (const int*)d_in[1];
    const float* emb   = (const float*)d_in[2];
    const float* W_ih  = (const float*)d_in[3];
    const float* W_hh  = (const float*)d_in[4];
    const float* b_ih  = (const float*)d_in[5];
    const float* b_hh  = (const float*)d_in[6];
    const float* W_out = (const float*)d_in[7];
    const float* b_out = (const float*)d_in[8];
    float*       out   = (float*)d_out;

    rnn_mfma_kernel<<<NBLK, NTHR, 0, stream>>>(x, xlen, emb, W_ih, W_hh,
                                               b_ih, b_hh, W_out, b_out, out);
}